// Round 4
// baseline (32.577 us; speedup 1.0000x reference)
//
#include <hip/hip_runtime.h>

#define NP 2990
#define NT 32
#define NC 21
#define NPROD 6          // producer blocks (6*512 = 3072 >= 2990 priors)
#define BS 512
#define TOKEN 0x13579BDF

// Segment boundaries: cumsum of SIZES[i]*BOXES[i] = 2166, 2766, 2916, 2970, 2986, 2990
__device__ __forceinline__ int segment_of(int p) {
    if (p < 2166) return 0;
    if (p < 2766) return 1;
    if (p < 2916) return 2;
    if (p < 2970) return 3;
    if (p < 2986) return 4;
    return 5;
}

// Workspace: NO per-launch initialization required (token-flag protocol).
struct Ws {
    int flag[NPROD];        // producer-done tokens
    int part[NPROD][24];    // per-producer baseline partial counts
    int packed[NP];         // pred | (ct_old << 8), per prior
};

__global__ __launch_bounds__(BS) void ssd_onekernel(
    const float* __restrict__ conf,     // conf_data[0] : [NP][NC]
    const float* __restrict__ priors,   // [NP][4] (cx,cy,w,h)
    const float* __restrict__ targets,  // targets[0] : [NT][5]
    Ws* __restrict__ ws,
    float* __restrict__ out)            // [6][4]
{
    __shared__ float s_tr[NT * 5];
    const int tid = threadIdx.x;
    const int b   = blockIdx.x;

    if (tid < NT * 5) s_tr[tid] = targets[tid];

    if (b < NPROD) {
        // ================= producer: 512 priors =================
        __shared__ int s_cnt[24];
        if (tid < 24) s_cnt[tid] = 0;
        __syncthreads();

        const int p = b * BS + tid;
        if (p < NP) {
            float4 pr = reinterpret_cast<const float4*>(priors)[p];
            float px1 = pr.x - pr.z * 0.5f;
            float py1 = pr.y - pr.w * 0.5f;
            float px2 = pr.x + pr.z * 0.5f;
            float py2 = pr.y + pr.w * 0.5f;
            float ab  = (px2 - px1) * (py2 - py1);

            float best = -1.0f; int bi = 0;
            #pragma unroll 4
            for (int t = 0; t < NT; ++t) {
                float tx1 = s_tr[t*5+0], ty1 = s_tr[t*5+1];
                float tx2 = s_tr[t*5+2], ty2 = s_tr[t*5+3];
                float ix = fmaxf(fminf(tx2, px2) - fmaxf(tx1, px1), 0.0f);
                float iy = fmaxf(fminf(ty2, py2) - fmaxf(ty1, py1), 0.0f);
                float inter = ix * iy;
                float aa = (tx2 - tx1) * (ty2 - ty1);
                float ov = inter / (aa + ab - inter);
                if (ov > best) { best = ov; bi = t; }   // strict > keeps first max
            }

            const float* cp = conf + p * NC;
            float bc = cp[0]; int pred = 0;
            #pragma unroll
            for (int c = 1; c < NC; ++c) {
                float v = cp[c];
                if (v > bc) { bc = v; pred = c; }       // strict > keeps first max
            }

            int ct = (best < 0.5f) ? 0 : ((int)s_tr[bi*5+4] + 1);
            ws->packed[p] = pred | (ct << 8);

            int seg = segment_of(p);
            bool eq = (ct == pred);
            atomicAdd(&s_cnt[seg * 4 + (eq ? 0 : 1)], 1);
            if (ct > 0) atomicAdd(&s_cnt[seg * 4 + (eq ? 2 : 3)], 1);
        }
        __syncthreads();
        if (tid < 24) ws->part[b][tid] = s_cnt[tid];

        __threadfence();                // agent-scope release: write back L2
        __syncthreads();                // all threads' fences complete
        if (tid == 0)
            __hip_atomic_store(&ws->flag[b], TOKEN,
                               __ATOMIC_RELEASE, __HIP_MEMORY_SCOPE_AGENT);
    } else {
        // ================= finalizer block =================
        __shared__ int s_bpi[NT];
        __shared__ int s_corr[24];
        __shared__ int s_base[24];
        if (tid < 24) s_corr[tid] = 0;
        __syncthreads();                // s_tr ready

        // ---- per-truth best prior: 8 waves x 4 truths, butterfly argmax ----
        const int wave = tid >> 6;
        const int lane = tid & 63;

        float tx1[4], ty1[4], tx2[4], ty2[4], aa[4], bx[4];
        int bi[4];
        #pragma unroll
        for (int k = 0; k < 4; ++k) {
            int t = wave * 4 + k;
            tx1[k] = s_tr[t*5+0]; ty1[k] = s_tr[t*5+1];
            tx2[k] = s_tr[t*5+2]; ty2[k] = s_tr[t*5+3];
            aa[k]  = (tx2[k] - tx1[k]) * (ty2[k] - ty1[k]);
            bx[k] = -1.0f; bi[k] = NP;
        }
        for (int p = lane; p < NP; p += 64) {
            float4 pr = reinterpret_cast<const float4*>(priors)[p];
            float px1 = pr.x - pr.z * 0.5f;
            float py1 = pr.y - pr.w * 0.5f;
            float px2 = pr.x + pr.z * 0.5f;
            float py2 = pr.y + pr.w * 0.5f;
            float ab  = (px2 - px1) * (py2 - py1);
            #pragma unroll
            for (int k = 0; k < 4; ++k) {
                float ix = fmaxf(fminf(tx2[k], px2) - fmaxf(tx1[k], px1), 0.0f);
                float iy = fmaxf(fminf(ty2[k], py2) - fmaxf(ty1[k], py1), 0.0f);
                float inter = ix * iy;
                float ov = inter / (aa[k] + ab - inter);
                if (ov > bx[k]) { bx[k] = ov; bi[k] = p; }   // lane-local first max
            }
        }
        #pragma unroll
        for (int k = 0; k < 4; ++k) {
            float bv = bx[k]; int bj = bi[k];
            #pragma unroll
            for (int off = 32; off > 0; off >>= 1) {
                float o = __shfl_xor(bv, off);
                int   j = __shfl_xor(bj, off);
                if (o > bv || (o == bv && j < bj)) { bv = o; bj = j; }
            }
            if (lane == 0) s_bpi[wave * 4 + k] = bj;
        }
        __syncthreads();

        // ---- wait for producers (token flags; no init needed) ----
        if (tid < NPROD) {
            while (__hip_atomic_load(&ws->flag[tid],
                                     __ATOMIC_ACQUIRE, __HIP_MEMORY_SCOPE_AGENT) != TOKEN)
                __builtin_amdgcn_s_sleep(1);
        }
        __syncthreads();
        __threadfence();

        // ---- sum baseline partials ----
        if (tid < 24) {
            int s = 0;
            #pragma unroll
            for (int q = 0; q < NPROD; ++q)
                s += __hip_atomic_load(&ws->part[q][tid],
                                       __ATOMIC_RELAXED, __HIP_MEMORY_SCOPE_AGENT);
            s_base[tid] = s;
        }

        // ---- last-wins scatter correction on <=32 priors ----
        if (tid < NT) {
            const int t = tid;
            const int p = s_bpi[t];
            bool winner = true;                       // last-wins dedup
            for (int u = t + 1; u < NT; ++u)
                if (s_bpi[u] == p) { winner = false; break; }
            if (winner) {
                int pk = __hip_atomic_load(&ws->packed[p],
                                           __ATOMIC_RELAXED, __HIP_MEMORY_SCOPE_AGENT);
                int pred   = pk & 0xff;
                int ct_old = pk >> 8;
                int ct_new = (int)s_tr[t*5+4] + 1;    // ov forced to 2.0; always > 0
                int seg = segment_of(p);
                atomicAdd(&s_corr[seg * 4 + ((ct_old == pred) ? 0 : 1)], -1);
                atomicAdd(&s_corr[seg * 4 + ((ct_new == pred) ? 0 : 1)],  1);
                if (ct_old > 0) atomicAdd(&s_corr[seg * 4 + ((ct_old == pred) ? 2 : 3)], -1);
                atomicAdd(&s_corr[seg * 4 + ((ct_new == pred) ? 2 : 3)],  1);
            }
        }
        __syncthreads();

        if (tid < 24) out[tid] = (float)(s_base[tid] + s_corr[tid]);
    }
}

extern "C" void kernel_launch(void* const* d_in, const int* in_sizes, int n_in,
                              void* d_out, int out_size, void* d_ws, size_t ws_size,
                              hipStream_t stream) {
    // Inputs (setup_inputs order): 0=loc_data (unused), 1=conf_data, 2=priors, 3=targets
    const float* conf    = (const float*)d_in[1];  // only batch 0 is read
    const float* priors  = (const float*)d_in[2];
    const float* targets = (const float*)d_in[3];  // only batch 0 is read
    float* out = (float*)d_out;
    Ws* ws = (Ws*)d_ws;

    hipLaunchKernelGGL(ssd_onekernel, dim3(NPROD + 1), dim3(BS), 0, stream,
                       conf, priors, targets, ws, out);
}

// Round 5
// 20.806 us; speedup vs baseline: 1.5658x; 1.5658x over previous
//
#include <hip/hip_runtime.h>

#define NP 2990
#define NT 32
#define NC 21
#define NPB 12   // prior blocks (12*256 >= 2990)

// Segment boundaries: cumsum of SIZES[i]*BOXES[i] = 2166, 2766, 2916, 2970, 2986, 2990
__device__ __forceinline__ int segment_of(int p) {
    if (p < 2166) return 0;
    if (p < 2766) return 1;
    if (p < 2916) return 2;
    if (p < 2970) return 3;
    if (p < 2986) return 4;
    return 5;
}

// Workspace: written by K1, read by K2 (stream order provides coherence).
struct Ws {
    int part[NPB][24];   // per-prior-block baseline partial counts
    int packed[NP];      // pred | (ct_old << 8), per prior
    int bpi[NT];         // best_prior_idx per truth
};

// K1: blocks 0..11 (256 thr): per-prior best-truth + pred argmax + partial counts.
//     blocks 12..19 (4 waves): one wave per truth, best-prior argmax.
__global__ __launch_bounds__(256) void k1_match(
    const float* __restrict__ conf,     // conf_data[0] : [NP][NC]
    const float* __restrict__ priors,   // [NP][4] (cx,cy,w,h)
    const float* __restrict__ targets,  // targets[0] : [NT][5]
    Ws* __restrict__ ws)
{
    const int b   = blockIdx.x;
    const int tid = threadIdx.x;

    if (b < NPB) {
        __shared__ float s_tr[NT * 5];
        __shared__ int   s_cnt[24];
        if (tid < NT * 5) s_tr[tid] = targets[tid];
        if (tid < 24)     s_cnt[tid] = 0;
        __syncthreads();

        const int p = b * 256 + tid;
        if (p < NP) {
            float4 pr = reinterpret_cast<const float4*>(priors)[p];
            float px1 = pr.x - pr.z * 0.5f;
            float py1 = pr.y - pr.w * 0.5f;
            float px2 = pr.x + pr.z * 0.5f;
            float py2 = pr.y + pr.w * 0.5f;
            float ab  = (px2 - px1) * (py2 - py1);

            float best = -1.0f; int bi = 0;
            #pragma unroll 4
            for (int t = 0; t < NT; ++t) {
                float tx1 = s_tr[t*5+0], ty1 = s_tr[t*5+1];
                float tx2 = s_tr[t*5+2], ty2 = s_tr[t*5+3];
                float ix = fmaxf(fminf(tx2, px2) - fmaxf(tx1, px1), 0.0f);
                float iy = fmaxf(fminf(ty2, py2) - fmaxf(ty1, py1), 0.0f);
                float inter = ix * iy;
                float aa = (tx2 - tx1) * (ty2 - ty1);
                float ov = inter / (aa + ab - inter);
                if (ov > best) { best = ov; bi = t; }   // strict > keeps first max
            }

            const float* cp = conf + p * NC;
            float bc = cp[0]; int pred = 0;
            #pragma unroll
            for (int c = 1; c < NC; ++c) {
                float v = cp[c];
                if (v > bc) { bc = v; pred = c; }       // strict > keeps first max
            }

            int ct = (best < 0.5f) ? 0 : ((int)s_tr[bi*5+4] + 1);
            ws->packed[p] = pred | (ct << 8);

            int seg = segment_of(p);
            bool eq = (ct == pred);
            atomicAdd(&s_cnt[seg * 4 + (eq ? 0 : 1)], 1);
            if (ct > 0) atomicAdd(&s_cnt[seg * 4 + (eq ? 2 : 3)], 1);
        }
        __syncthreads();
        if (tid < 24) ws->part[b][tid] = s_cnt[tid];
    } else {
        // one wave per truth: blocks 12..19 x 4 waves = 32 truths
        const int wave = tid >> 6;
        const int lane = tid & 63;
        const int t = (b - NPB) * 4 + wave;

        const float tx1 = targets[t*5+0], ty1 = targets[t*5+1];
        const float tx2 = targets[t*5+2], ty2 = targets[t*5+3];
        const float aa  = (tx2 - tx1) * (ty2 - ty1);

        float best = -1.0f; int bi = NP;
        for (int p = lane; p < NP; p += 64) {
            float4 pr = reinterpret_cast<const float4*>(priors)[p];
            float px1 = pr.x - pr.z * 0.5f;
            float py1 = pr.y - pr.w * 0.5f;
            float px2 = pr.x + pr.z * 0.5f;
            float py2 = pr.y + pr.w * 0.5f;
            float ab  = (px2 - px1) * (py2 - py1);

            float ix = fmaxf(fminf(tx2, px2) - fmaxf(tx1, px1), 0.0f);
            float iy = fmaxf(fminf(ty2, py2) - fmaxf(ty1, py1), 0.0f);
            float inter = ix * iy;
            float ov = inter / (aa + ab - inter);
            if (ov > best) { best = ov; bi = p; }       // lane-local first max
        }
        // 64-lane butterfly argmax; min-index tie-break => global first-occurrence
        #pragma unroll
        for (int off = 32; off > 0; off >>= 1) {
            float o = __shfl_xor(best, off);
            int   j = __shfl_xor(bi,   off);
            if (o > best || (o == best && j < bi)) { best = o; bi = j; }
        }
        if (lane == 0) ws->bpi[t] = bi;
    }
}

// K2: one wave — sum partials + last-wins scatter correction on <=32 priors.
__global__ __launch_bounds__(64) void k2_final(
    const float* __restrict__ targets,
    const Ws* __restrict__ ws,
    float* __restrict__ out)            // [6][4]
{
    __shared__ int s_corr[24];
    __shared__ int s_base[24];
    __shared__ int s_bpi[NT];

    const int tid = threadIdx.x;

    if (tid < 24) s_corr[tid] = 0;
    if (tid < NT) s_bpi[tid] = ws->bpi[tid];
    __syncthreads();

    if (tid < 24) {
        int s = 0;
        #pragma unroll
        for (int q = 0; q < NPB; ++q) s += ws->part[q][tid];
        s_base[tid] = s;
    }

    if (tid < NT) {
        const int t = tid;
        const int p = s_bpi[t];
        bool winner = true;                       // last-wins dedup
        for (int u = t + 1; u < NT; ++u)
            if (s_bpi[u] == p) { winner = false; break; }
        if (winner) {
            int pk     = ws->packed[p];
            int pred   = pk & 0xff;
            int ct_old = pk >> 8;
            int ct_new = (int)targets[t*5+4] + 1; // ov forced to 2.0; always > 0
            int seg = segment_of(p);
            atomicAdd(&s_corr[seg * 4 + ((ct_old == pred) ? 0 : 1)], -1);
            atomicAdd(&s_corr[seg * 4 + ((ct_new == pred) ? 0 : 1)],  1);
            if (ct_old > 0) atomicAdd(&s_corr[seg * 4 + ((ct_old == pred) ? 2 : 3)], -1);
            atomicAdd(&s_corr[seg * 4 + ((ct_new == pred) ? 2 : 3)],  1);
        }
    }
    __syncthreads();

    if (tid < 24) out[tid] = (float)(s_base[tid] + s_corr[tid]);
}

extern "C" void kernel_launch(void* const* d_in, const int* in_sizes, int n_in,
                              void* d_out, int out_size, void* d_ws, size_t ws_size,
                              hipStream_t stream) {
    // Inputs (setup_inputs order): 0=loc_data (unused), 1=conf_data, 2=priors, 3=targets
    const float* conf    = (const float*)d_in[1];  // only batch 0 is read
    const float* priors  = (const float*)d_in[2];
    const float* targets = (const float*)d_in[3];  // only batch 0 is read
    float* out = (float*)d_out;
    Ws* ws = (Ws*)d_ws;

    hipLaunchKernelGGL(k1_match, dim3(20), dim3(256), 0, stream, conf, priors, targets, ws);
    hipLaunchKernelGGL(k2_final, dim3(1), dim3(64), 0, stream, targets, ws, out);
}

// Round 6
// 15.977 us; speedup vs baseline: 2.0390x; 1.3022x over previous
//
#include <hip/hip_runtime.h>

#define NP 2990
#define NT 32
#define NC 21
#define NPB 24          // producer blocks, 128 priors each (24*128 = 3072 >= 2990)
#define K1_BLOCKS (NPB + NT)   // 24 producers + 32 truth blocks

// Segment boundaries: cumsum of SIZES[i]*BOXES[i] = 2166, 2766, 2916, 2970, 2986, 2990
__device__ __forceinline__ int segment_of(int p) {
    if (p < 2166) return 0;
    if (p < 2766) return 1;
    if (p < 2916) return 2;
    if (p < 2970) return 3;
    if (p < 2986) return 4;
    return 5;
}

// Workspace: written by K1, read by K2 (stream order provides coherence).
struct Ws {
    int part[NPB][24];   // per-producer-block baseline partial counts
    int packed[NP];      // pred | (ct_old << 8), per prior
    int bpi[NT];         // best_prior_idx per truth
};

// K1: blocks 0..23 (128 thr): 128 priors each — best-truth + pred argmax + partials.
//     blocks 24..55 (128 thr): one truth each — best-prior argmax (2 waves + merge).
__global__ __launch_bounds__(128) void k1_match(
    const float* __restrict__ conf,     // conf_data[0] : [NP][NC]
    const float* __restrict__ priors,   // [NP][4] (cx,cy,w,h)
    const float* __restrict__ targets,  // targets[0] : [NT][5]
    Ws* __restrict__ ws)
{
    const int b   = blockIdx.x;
    const int tid = threadIdx.x;

    if (b < NPB) {
        // ============ producer: 128 priors, LDS-staged conf ============
        __shared__ float s_conf[128 * NC];   // 10752 B
        __shared__ float s_tr[NT * 5];
        __shared__ int   s_cnt[24];

        const int p0 = b * 128;
        // coalesced float4 staging: slice starts at byte p0*84 = b*10752 (16B-aligned)
        const float4* g4 = reinterpret_cast<const float4*>(conf + (size_t)p0 * NC);
        float4* l4 = reinterpret_cast<float4*>(s_conf);
        #pragma unroll
        for (int k = 0; k < 6; ++k) {
            int idx = tid + k * 128;
            if (idx < (128 * NC) / 4) l4[idx] = g4[idx];   // safe over-read: batch>=2 exists
        }
        if (tid < NT * 5) s_tr[tid] = targets[tid];
        if (tid < 24)     s_cnt[tid] = 0;
        __syncthreads();

        const int p = p0 + tid;
        if (p < NP) {
            float4 pr = reinterpret_cast<const float4*>(priors)[p];
            float px1 = pr.x - pr.z * 0.5f;
            float py1 = pr.y - pr.w * 0.5f;
            float px2 = pr.x + pr.z * 0.5f;
            float py2 = pr.y + pr.w * 0.5f;
            float ab  = (px2 - px1) * (py2 - py1);

            // two 16-truth chains (ILP=2); merge: strict > so first half wins ties
            float b0 = -1.0f, b1 = -1.0f; int i0 = 0, i1 = 16;
            #pragma unroll 4
            for (int t = 0; t < 16; ++t) {
                {
                    float tx1 = s_tr[t*5+0], ty1 = s_tr[t*5+1];
                    float tx2 = s_tr[t*5+2], ty2 = s_tr[t*5+3];
                    float ix = fmaxf(fminf(tx2, px2) - fmaxf(tx1, px1), 0.0f);
                    float iy = fmaxf(fminf(ty2, py2) - fmaxf(ty1, py1), 0.0f);
                    float inter = ix * iy;
                    float aa = (tx2 - tx1) * (ty2 - ty1);
                    float ov = inter / (aa + ab - inter);
                    if (ov > b0) { b0 = ov; i0 = t; }
                }
                {
                    int u = t + 16;
                    float tx1 = s_tr[u*5+0], ty1 = s_tr[u*5+1];
                    float tx2 = s_tr[u*5+2], ty2 = s_tr[u*5+3];
                    float ix = fmaxf(fminf(tx2, px2) - fmaxf(tx1, px1), 0.0f);
                    float iy = fmaxf(fminf(ty2, py2) - fmaxf(ty1, py1), 0.0f);
                    float inter = ix * iy;
                    float aa = (tx2 - tx1) * (ty2 - ty1);
                    float ov = inter / (aa + ab - inter);
                    if (ov > b1) { b1 = ov; i1 = u; }
                }
            }
            float best = b0; int bi = i0;
            if (b1 > best) { best = b1; bi = i1; }   // strict >: first-occurrence

            // pred argmax from LDS row; two chains (0..9, 10..20), strict > merge
            const float* cp = &s_conf[tid * NC];
            float bcA = cp[0]; int pA = 0;
            float bcB = cp[10]; int pB = 10;
            #pragma unroll
            for (int c = 1; c < 10; ++c) {
                float vA = cp[c];      if (vA > bcA) { bcA = vA; pA = c; }
                float vB = cp[c + 10]; if (vB > bcB) { bcB = vB; pB = c + 10; }
            }
            { float vB = cp[20]; if (vB > bcB) { bcB = vB; pB = 20; } }
            float bc = bcA; int pred = pA;
            if (bcB > bc) { bc = bcB; pred = pB; }   // strict >: first-occurrence

            int ct = (best < 0.5f) ? 0 : ((int)s_tr[bi*5+4] + 1);
            ws->packed[p] = pred | (ct << 8);

            int seg = segment_of(p);
            bool eq = (ct == pred);
            atomicAdd(&s_cnt[seg * 4 + (eq ? 0 : 1)], 1);
            if (ct > 0) atomicAdd(&s_cnt[seg * 4 + (eq ? 2 : 3)], 1);
        }
        __syncthreads();
        if (tid < 24) ws->part[b][tid] = s_cnt[tid];
    } else {
        // ============ truth block: one truth, 2 waves + LDS merge ============
        __shared__ float s_v[2];
        __shared__ int   s_i[2];
        const int t    = b - NPB;
        const int wave = tid >> 6;
        const int lane = tid & 63;

        const float tx1 = targets[t*5+0], ty1 = targets[t*5+1];
        const float tx2 = targets[t*5+2], ty2 = targets[t*5+3];
        const float aa  = (tx2 - tx1) * (ty2 - ty1);

        float bv = -1.0f; int bj = NP;
        for (int p = tid; p < NP; p += 128) {
            float4 pr = reinterpret_cast<const float4*>(priors)[p];
            float px1 = pr.x - pr.z * 0.5f;
            float py1 = pr.y - pr.w * 0.5f;
            float px2 = pr.x + pr.z * 0.5f;
            float py2 = pr.y + pr.w * 0.5f;
            float ab  = (px2 - px1) * (py2 - py1);

            float ix = fmaxf(fminf(tx2, px2) - fmaxf(tx1, px1), 0.0f);
            float iy = fmaxf(fminf(ty2, py2) - fmaxf(ty1, py1), 0.0f);
            float inter = ix * iy;
            float ov = inter / (aa + ab - inter);
            if (ov > bv) { bv = ov; bj = p; }        // lane-local first max
        }
        // 64-lane butterfly argmax; min-index tie-break
        #pragma unroll
        for (int off = 32; off > 0; off >>= 1) {
            float o = __shfl_xor(bv, off);
            int   j = __shfl_xor(bj, off);
            if (o > bv || (o == bv && j < bj)) { bv = o; bj = j; }
        }
        if (lane == 0) { s_v[wave] = bv; s_i[wave] = bj; }
        __syncthreads();
        if (tid == 0) {
            float v = s_v[0]; int i = s_i[0];
            if (s_v[1] > v || (s_v[1] == v && s_i[1] < i)) { v = s_v[1]; i = s_i[1]; }
            ws->bpi[t] = i;
        }
    }
}

// K2: one wave — sum partials + last-wins scatter correction on <=32 priors.
__global__ __launch_bounds__(64) void k2_final(
    const float* __restrict__ targets,
    const Ws* __restrict__ ws,
    float* __restrict__ out)            // [6][4]
{
    __shared__ int s_corr[24];
    __shared__ int s_base[24];
    __shared__ int s_bpi[NT];

    const int tid = threadIdx.x;

    if (tid < 24) s_corr[tid] = 0;
    if (tid < NT) s_bpi[tid] = ws->bpi[tid];
    __syncthreads();

    if (tid < 24) {
        int s = 0;
        #pragma unroll
        for (int q = 0; q < NPB; ++q) s += ws->part[q][tid];
        s_base[tid] = s;
    }

    if (tid < NT) {
        const int t = tid;
        const int p = s_bpi[t];
        bool winner = true;                       // last-wins dedup
        for (int u = t + 1; u < NT; ++u)
            if (s_bpi[u] == p) { winner = false; break; }
        if (winner) {
            int pk     = ws->packed[p];
            int pred   = pk & 0xff;
            int ct_old = pk >> 8;
            int ct_new = (int)targets[t*5+4] + 1; // ov forced to 2.0; always > 0
            int seg = segment_of(p);
            atomicAdd(&s_corr[seg * 4 + ((ct_old == pred) ? 0 : 1)], -1);
            atomicAdd(&s_corr[seg * 4 + ((ct_new == pred) ? 0 : 1)],  1);
            if (ct_old > 0) atomicAdd(&s_corr[seg * 4 + ((ct_old == pred) ? 2 : 3)], -1);
            atomicAdd(&s_corr[seg * 4 + ((ct_new == pred) ? 2 : 3)],  1);
        }
    }
    __syncthreads();

    if (tid < 24) out[tid] = (float)(s_base[tid] + s_corr[tid]);
}

extern "C" void kernel_launch(void* const* d_in, const int* in_sizes, int n_in,
                              void* d_out, int out_size, void* d_ws, size_t ws_size,
                              hipStream_t stream) {
    // Inputs (setup_inputs order): 0=loc_data (unused), 1=conf_data, 2=priors, 3=targets
    const float* conf    = (const float*)d_in[1];  // only batch 0 is read
    const float* priors  = (const float*)d_in[2];
    const float* targets = (const float*)d_in[3];  // only batch 0 is read
    float* out = (float*)d_out;
    Ws* ws = (Ws*)d_ws;

    hipLaunchKernelGGL(k1_match, dim3(K1_BLOCKS), dim3(128), 0, stream,
                       conf, priors, targets, ws);
    hipLaunchKernelGGL(k2_final, dim3(1), dim3(64), 0, stream, targets, ws, out);
}

// Round 7
// 15.915 us; speedup vs baseline: 2.0470x; 1.0039x over previous
//
#include <hip/hip_runtime.h>

#define NP 2990
#define NT 32
#define NC 21
#define NPB 24          // producer blocks, 128 priors each (24*128 = 3072 >= 2990)
#define K1_BLOCKS (NPB + NT)   // 24 producers + 32 truth blocks

// Segment boundaries: cumsum of SIZES[i]*BOXES[i] = 2166, 2766, 2916, 2970, 2986, 2990
__device__ __forceinline__ int segment_of(int p) {
    if (p < 2166) return 0;
    if (p < 2766) return 1;
    if (p < 2916) return 2;
    if (p < 2970) return 3;
    if (p < 2986) return 4;
    return 5;
}

// Workspace: written by K1, read by K2 (stream order provides coherence).
struct Ws {
    int part[NPB][24];   // per-producer-block baseline partial counts
    int packed[NP];      // pred | (ct_old << 8), per prior
    int bpi[NT];         // best_prior_idx per truth
};

// K1: blocks 0..23 (128 thr): 128 priors each — best-truth + pred argmax + partials.
//     blocks 24..55 (128 thr): one truth each — best-prior argmax (2 waves + merge).
__global__ __launch_bounds__(128) void k1_match(
    const float* __restrict__ conf,     // conf_data[0] : [NP][NC]
    const float* __restrict__ priors,   // [NP][4] (cx,cy,w,h)
    const float* __restrict__ targets,  // targets[0] : [NT][5]
    Ws* __restrict__ ws)
{
    const int b   = blockIdx.x;
    const int tid = threadIdx.x;

    if (b < NPB) {
        // ============ producer: 128 priors, LDS-staged conf ============
        __shared__ float s_conf[128 * NC];   // 10752 B
        __shared__ float s_tr[NT * 5];
        __shared__ int   s_cnt[24];

        const int p0 = b * 128;
        // coalesced float4 staging: slice starts at byte p0*84 = b*10752 (16B-aligned)
        const float4* g4 = reinterpret_cast<const float4*>(conf + (size_t)p0 * NC);
        float4* l4 = reinterpret_cast<float4*>(s_conf);
        #pragma unroll
        for (int k = 0; k < 6; ++k) {
            int idx = tid + k * 128;
            if (idx < (128 * NC) / 4) l4[idx] = g4[idx];   // safe over-read: batch>=2 exists
        }
        // BUG FIX (R6): NT*5=160 > blockDim 128 — must stride, not single-shot
        for (int i = tid; i < NT * 5; i += 128) s_tr[i] = targets[i];
        if (tid < 24) s_cnt[tid] = 0;
        __syncthreads();

        const int p = p0 + tid;
        if (p < NP) {
            float4 pr = reinterpret_cast<const float4*>(priors)[p];
            float px1 = pr.x - pr.z * 0.5f;
            float py1 = pr.y - pr.w * 0.5f;
            float px2 = pr.x + pr.z * 0.5f;
            float py2 = pr.y + pr.w * 0.5f;
            float ab  = (px2 - px1) * (py2 - py1);

            // two 16-truth chains (ILP=2); merge: strict > so first half wins ties
            float b0 = -1.0f, b1 = -1.0f; int i0 = 0, i1 = 16;
            #pragma unroll 4
            for (int t = 0; t < 16; ++t) {
                {
                    float tx1 = s_tr[t*5+0], ty1 = s_tr[t*5+1];
                    float tx2 = s_tr[t*5+2], ty2 = s_tr[t*5+3];
                    float ix = fmaxf(fminf(tx2, px2) - fmaxf(tx1, px1), 0.0f);
                    float iy = fmaxf(fminf(ty2, py2) - fmaxf(ty1, py1), 0.0f);
                    float inter = ix * iy;
                    float aa = (tx2 - tx1) * (ty2 - ty1);
                    float ov = inter / (aa + ab - inter);
                    if (ov > b0) { b0 = ov; i0 = t; }
                }
                {
                    int u = t + 16;
                    float tx1 = s_tr[u*5+0], ty1 = s_tr[u*5+1];
                    float tx2 = s_tr[u*5+2], ty2 = s_tr[u*5+3];
                    float ix = fmaxf(fminf(tx2, px2) - fmaxf(tx1, px1), 0.0f);
                    float iy = fmaxf(fminf(ty2, py2) - fmaxf(ty1, py1), 0.0f);
                    float inter = ix * iy;
                    float aa = (tx2 - tx1) * (ty2 - ty1);
                    float ov = inter / (aa + ab - inter);
                    if (ov > b1) { b1 = ov; i1 = u; }
                }
            }
            float best = b0; int bi = i0;
            if (b1 > best) { best = b1; bi = i1; }   // strict >: first-occurrence

            // pred argmax from LDS row; two chains (0..9, 10..20), strict > merge
            const float* cp = &s_conf[tid * NC];
            float bcA = cp[0]; int pA = 0;
            float bcB = cp[10]; int pB = 10;
            #pragma unroll
            for (int c = 1; c < 10; ++c) {
                float vA = cp[c];      if (vA > bcA) { bcA = vA; pA = c; }
                float vB = cp[c + 10]; if (vB > bcB) { bcB = vB; pB = c + 10; }
            }
            { float vB = cp[20]; if (vB > bcB) { bcB = vB; pB = 20; } }
            float bc = bcA; int pred = pA;
            if (bcB > bc) { bc = bcB; pred = pB; }   // strict >: first-occurrence

            int ct = (best < 0.5f) ? 0 : ((int)s_tr[bi*5+4] + 1);
            ws->packed[p] = pred | (ct << 8);

            int seg = segment_of(p);
            bool eq = (ct == pred);
            atomicAdd(&s_cnt[seg * 4 + (eq ? 0 : 1)], 1);
            if (ct > 0) atomicAdd(&s_cnt[seg * 4 + (eq ? 2 : 3)], 1);
        }
        __syncthreads();
        if (tid < 24) ws->part[b][tid] = s_cnt[tid];
    } else {
        // ============ truth block: one truth, 2 waves + LDS merge ============
        __shared__ float s_v[2];
        __shared__ int   s_i[2];
        const int t    = b - NPB;
        const int wave = tid >> 6;
        const int lane = tid & 63;

        const float tx1 = targets[t*5+0], ty1 = targets[t*5+1];
        const float tx2 = targets[t*5+2], ty2 = targets[t*5+3];
        const float aa  = (tx2 - tx1) * (ty2 - ty1);

        float bv = -1.0f; int bj = NP;
        for (int p = tid; p < NP; p += 128) {
            float4 pr = reinterpret_cast<const float4*>(priors)[p];
            float px1 = pr.x - pr.z * 0.5f;
            float py1 = pr.y - pr.w * 0.5f;
            float px2 = pr.x + pr.z * 0.5f;
            float py2 = pr.y + pr.w * 0.5f;
            float ab  = (px2 - px1) * (py2 - py1);

            float ix = fmaxf(fminf(tx2, px2) - fmaxf(tx1, px1), 0.0f);
            float iy = fmaxf(fminf(ty2, py2) - fmaxf(ty1, py1), 0.0f);
            float inter = ix * iy;
            float ov = inter / (aa + ab - inter);
            if (ov > bv) { bv = ov; bj = p; }        // lane-local first max
        }
        // 64-lane butterfly argmax; min-index tie-break
        #pragma unroll
        for (int off = 32; off > 0; off >>= 1) {
            float o = __shfl_xor(bv, off);
            int   j = __shfl_xor(bj, off);
            if (o > bv || (o == bv && j < bj)) { bv = o; bj = j; }
        }
        if (lane == 0) { s_v[wave] = bv; s_i[wave] = bj; }
        __syncthreads();
        if (tid == 0) {
            float v = s_v[0]; int i = s_i[0];
            if (s_v[1] > v || (s_v[1] == v && s_i[1] < i)) { v = s_v[1]; i = s_i[1]; }
            ws->bpi[t] = i;
        }
    }
}

// K2: one wave — sum partials + last-wins scatter correction on <=32 priors.
__global__ __launch_bounds__(64) void k2_final(
    const float* __restrict__ targets,
    const Ws* __restrict__ ws,
    float* __restrict__ out)            // [6][4]
{
    __shared__ int s_corr[24];
    __shared__ int s_base[24];
    __shared__ int s_bpi[NT];

    const int tid = threadIdx.x;

    if (tid < 24) s_corr[tid] = 0;
    if (tid < NT) s_bpi[tid] = ws->bpi[tid];
    __syncthreads();

    if (tid < 24) {
        int s = 0;
        #pragma unroll
        for (int q = 0; q < NPB; ++q) s += ws->part[q][tid];
        s_base[tid] = s;
    }

    if (tid < NT) {
        const int t = tid;
        const int p = s_bpi[t];
        bool winner = true;                       // last-wins dedup
        for (int u = t + 1; u < NT; ++u)
            if (s_bpi[u] == p) { winner = false; break; }
        if (winner) {
            int pk     = ws->packed[p];
            int pred   = pk & 0xff;
            int ct_old = pk >> 8;
            int ct_new = (int)targets[t*5+4] + 1; // ov forced to 2.0; always > 0
            int seg = segment_of(p);
            atomicAdd(&s_corr[seg * 4 + ((ct_old == pred) ? 0 : 1)], -1);
            atomicAdd(&s_corr[seg * 4 + ((ct_new == pred) ? 0 : 1)],  1);
            if (ct_old > 0) atomicAdd(&s_corr[seg * 4 + ((ct_old == pred) ? 2 : 3)], -1);
            atomicAdd(&s_corr[seg * 4 + ((ct_new == pred) ? 2 : 3)],  1);
        }
    }
    __syncthreads();

    if (tid < 24) out[tid] = (float)(s_base[tid] + s_corr[tid]);
}

extern "C" void kernel_launch(void* const* d_in, const int* in_sizes, int n_in,
                              void* d_out, int out_size, void* d_ws, size_t ws_size,
                              hipStream_t stream) {
    // Inputs (setup_inputs order): 0=loc_data (unused), 1=conf_data, 2=priors, 3=targets
    const float* conf    = (const float*)d_in[1];  // only batch 0 is read
    const float* priors  = (const float*)d_in[2];
    const float* targets = (const float*)d_in[3];  // only batch 0 is read
    float* out = (float*)d_out;
    Ws* ws = (Ws*)d_ws;

    hipLaunchKernelGGL(k1_match, dim3(K1_BLOCKS), dim3(128), 0, stream,
                       conf, priors, targets, ws);
    hipLaunchKernelGGL(k2_final, dim3(1), dim3(64), 0, stream, targets, ws, out);
}